// Round 16
// baseline (313.775 us; speedup 1.0000x reference)
//
#include <hip/hip_runtime.h>
#include <hip/hip_bf16.h>

typedef short  s16x8 __attribute__((ext_vector_type(8)));
typedef float  f32x4 __attribute__((ext_vector_type(4)));
typedef long   l64x2 __attribute__((ext_vector_type(2)));
typedef unsigned long long u64t;

#define KBONES 64
#define HDIM   256
#define KP1    96     // padded K for layer 1 (67 -> 96)
#define BM     128    // vertices per block (mlp kernel)
#define HST    264    // bf16 LDS row stride (fallback kernel)
#define HSTB   264    // fp8 LDS row stride in BYTES: 66 dw % 32 = 2 -> conflict-free b64 reads

__device__ __forceinline__ unsigned short f2bf(float f) {
  unsigned int u = __float_as_uint(f);
  u += 0x7FFFu + ((u >> 16) & 1u);       // RNE (finite values only here)
  return (unsigned short)(u >> 16);
}
__device__ __forceinline__ float bf2f(unsigned short u) {
  union { unsigned int i; float f; } x; x.i = ((unsigned int)u) << 16; return x.f;
}
// HW fp8 conversion: v_cvt_pk_fp8_f32 (OCP e4m3 on gfx950, RNE + saturate).
__device__ __forceinline__ unsigned int cvt2fp8(float a, float b) {
  return ((unsigned int)__builtin_amdgcn_cvt_pk_fp8_f32(a, b, 0, false)) & 0xFFFFu;
}
__device__ __forceinline__ unsigned char f2fp8(float f) {
  return (unsigned char)(cvt2fp8(f, 0.f) & 0xFFu);
}

// ---------------- prep: rotations + bf16 (fallback) + fp8 (main) weights ----------------
// rotw layout: [k][12] = {R row-major 0..8, t 9..11}
__global__ void prep_kernel(const float* __restrict__ rot6d,
                            const float* __restrict__ trans,
                            const float* __restrict__ W1,
                            const float* __restrict__ W2,
                            const float* __restrict__ W3,
                            const float* __restrict__ W4,
                            float* __restrict__ rotw,
                            unsigned short* __restrict__ W1t,
                            unsigned short* __restrict__ W2t,
                            unsigned short* __restrict__ W3t,
                            unsigned char* __restrict__ W1f,
                            unsigned char* __restrict__ W2f,
                            unsigned char* __restrict__ W3f,
                            unsigned char* __restrict__ W4f) {
  int tid = blockIdx.x * blockDim.x + threadIdx.x;
  int stride = gridDim.x * blockDim.x;
  if (tid < KBONES) {
    int k = tid;
    float a10 = rot6d[k*6+0], a11 = rot6d[k*6+1], a12 = rot6d[k*6+2];
    float a20 = rot6d[k*6+3], a21 = rot6d[k*6+4], a22 = rot6d[k*6+5];
    float n1 = fmaxf(sqrtf(a10*a10 + a11*a11 + a12*a12), 1e-12f);
    float b1x = a10/n1, b1y = a11/n1, b1z = a12/n1;
    float d  = b1x*a20 + b1y*a21 + b1z*a22;
    float c0 = a20 - d*b1x, c1 = a21 - d*b1y, c2 = a22 - d*b1z;
    float n2 = fmaxf(sqrtf(c0*c0 + c1*c1 + c2*c2), 1e-12f);
    float b2x = c0/n2, b2y = c1/n2, b2z = c2/n2;
    float b3x = b1y*b2z - b1z*b2y;
    float b3y = b1z*b2x - b1x*b2z;
    float b3z = b1x*b2y - b1y*b2x;
    rotw[k*12+0]=b1x; rotw[k*12+1]=b2x; rotw[k*12+2]=b3x;
    rotw[k*12+3]=b1y; rotw[k*12+4]=b2y; rotw[k*12+5]=b3y;
    rotw[k*12+6]=b1z; rotw[k*12+7]=b2z; rotw[k*12+8]=b3z;
    rotw[k*12+9]=trans[k*3+0]; rotw[k*12+10]=trans[k*3+1]; rotw[k*12+11]=trans[k*3+2];
  }
  // [h][kk]: kk 0..63 = w (W1 row 3+kk), 64..66 = local_p (W1 row kk-64), 67..95 = 0
  for (int i = tid; i < HDIM*KP1; i += stride) {
    int h = i / KP1, kk = i % KP1;
    float v = (kk < 64) ? W1[(size_t)(3+kk)*HDIM + h]
            : (kk < 67) ? W1[(size_t)(kk-64)*HDIM + h] : 0.f;
    W1t[i] = f2bf(v);
    W1f[i] = f2fp8(v);
  }
  for (int i = tid; i < HDIM*HDIM; i += stride) {
    int h2 = i / HDIM, h1 = i % HDIM;
    float v2 = W2[(size_t)h1*HDIM + h2];
    float v3 = W3[(size_t)h1*HDIM + h2];
    W2t[i] = f2bf(v2);  W2f[i] = f2fp8(v2);
    W3t[i] = f2bf(v3);  W3f[i] = f2fp8(v3);
  }
  // W4f[j][h], j padded 3->16
  for (int i = tid; i < 16*HDIM; i += stride) {
    int j = i / HDIM, h = i % HDIM;
    W4f[i] = (j < 3) ? f2fp8(W4[(size_t)h*3 + j]) : (unsigned char)0;
  }
}

// ---------------- per-vertex polar rotation (matches U diag(1,1,s) Vh) ----------------
__device__ __forceinline__ void polar_rotation(const float M[9], float R[9]) {
  float a00 = M[0]*M[0] + M[3]*M[3] + M[6]*M[6];
  float a01 = M[0]*M[1] + M[3]*M[4] + M[6]*M[7];
  float a02 = M[0]*M[2] + M[3]*M[5] + M[6]*M[8];
  float a11 = M[1]*M[1] + M[4]*M[4] + M[7]*M[7];
  float a12 = M[1]*M[2] + M[4]*M[5] + M[7]*M[8];
  float a22 = M[2]*M[2] + M[5]*M[5] + M[8]*M[8];
  float v00=1.f,v01=0.f,v02=0.f, v10=0.f,v11=1.f,v12=0.f, v20=0.f,v21=0.f,v22=1.f;

#define JROT(APP,AQQ,APQ,APR,AQR, VP0,VQ0, VP1,VQ1, VP2,VQ2)                     \
  {                                                                              \
    float apq = APQ;                                                             \
    if (fabsf(apq) > 1e-25f) {                                                   \
      float tau = (AQQ - APP) / (2.f * apq);                                     \
      float tt  = copysignf(1.f / (fabsf(tau) + sqrtf(1.f + tau*tau)), tau);     \
      float c   = 1.f / sqrtf(1.f + tt*tt);                                      \
      float s   = tt * c;                                                        \
      APP -= tt * apq; AQQ += tt * apq; APQ = 0.f;                               \
      float pr = APR, qr = AQR;                                                  \
      APR = c*pr - s*qr; AQR = s*pr + c*qr;                                      \
      float t0;                                                                  \
      t0 = VP0; VP0 = c*t0 - s*VQ0; VQ0 = s*t0 + c*VQ0;                          \
      t0 = VP1; VP1 = c*t0 - s*VQ1; VQ1 = s*t0 + c*VQ1;                          \
      t0 = VP2; VP2 = c*t0 - s*VQ2; VQ2 = s*t0 + c*VQ2;                          \
    }                                                                            \
  }

  #pragma unroll
  for (int sweep = 0; sweep < 5; ++sweep) {
    JROT(a00, a11, a01, a02, a12, v00,v01, v10,v11, v20,v21)
    JROT(a00, a22, a02, a01, a12, v00,v02, v10,v12, v20,v22)
    JROT(a11, a22, a12, a01, a02, v01,v02, v11,v12, v21,v22)
  }
#undef JROT

  float l0=a00, l1=a11, l2=a22;
  float e0x=v00,e0y=v10,e0z=v20;
  float e1x=v01,e1y=v11,e1z=v21;
  float e2x=v02,e2y=v12,e2z=v22;
  float tf;
  if (l0 < l1) { tf=l0;l0=l1;l1=tf; tf=e0x;e0x=e1x;e1x=tf; tf=e0y;e0y=e1y;e1y=tf; tf=e0z;e0z=e1z;e1z=tf; }
  if (l0 < l2) { tf=l0;l0=l2;l2=tf; tf=e0x;e0x=e2x;e2x=tf; tf=e0y;e0y=e2y;e2y=tf; tf=e0z;e0z=e2z;e2z=tf; }
  if (l1 < l2) { tf=l1;l1=l2;l2=tf; tf=e1x;e1x=e2x;e2x=tf; tf=e1y;e1y=e2y;e2y=tf; tf=e1z;e1z=e2z;e2z=tf; }

  float u1x = M[0]*e0x + M[1]*e0y + M[2]*e0z;
  float u1y = M[3]*e0x + M[4]*e0y + M[5]*e0z;
  float u1z = M[6]*e0x + M[7]*e0y + M[8]*e0z;
  float i1 = 1.f / fmaxf(sqrtf(u1x*u1x + u1y*u1y + u1z*u1z), 1e-25f);
  u1x*=i1; u1y*=i1; u1z*=i1;
  float u2x = M[0]*e1x + M[1]*e1y + M[2]*e1z;
  float u2y = M[3]*e1x + M[4]*e1y + M[5]*e1z;
  float u2z = M[6]*e1x + M[7]*e1y + M[8]*e1z;
  float dd = u1x*u2x + u1y*u2y + u1z*u2z;
  u2x -= dd*u1x; u2y -= dd*u1y; u2z -= dd*u1z;
  float i2 = 1.f / fmaxf(sqrtf(u2x*u2x + u2y*u2y + u2z*u2z), 1e-25f);
  u2x*=i2; u2y*=i2; u2z*=i2;
  float u3x = u1y*u2z - u1z*u2y;
  float u3y = u1z*u2x - u1x*u2z;
  float u3z = u1x*u2y - u1y*u2x;
  float w2x = e0y*e1z - e0z*e1y;
  float w2y = e0z*e1x - e0x*e1z;
  float w2z = e0x*e1y - e0y*e1x;
  R[0] = u1x*e0x + u2x*e1x + u3x*w2x;
  R[1] = u1x*e0y + u2x*e1y + u3x*w2y;
  R[2] = u1x*e0z + u2x*e1z + u3x*w2z;
  R[3] = u1y*e0x + u2y*e1x + u3y*w2x;
  R[4] = u1y*e0y + u2y*e1y + u3y*w2y;
  R[5] = u1y*e0z + u2y*e1z + u3y*w2z;
  R[6] = u1z*e0x + u2z*e1x + u3z*w2x;
  R[7] = u1z*e0y + u2z*e1y + u3z*w2y;
  R[8] = u1z*e0z + u2z*e1z + u3z*w2z;
}

// ---------------- kernel 2: one thread per vertex (softmax, blend, SVD) ----------------
// Pass-1 unroll 4 (ILP for HBM latency) — proven r13/r14.
__global__ __launch_bounds__(256) void vertex_kernel(
                              const float* __restrict__ verts,
                              const float* __restrict__ logits,
                              const float* __restrict__ rotw,
                              unsigned char* __restrict__ Xg,
                              float* __restrict__ RbS,
                              float* __restrict__ out, int N) {
  __shared__ float rotL[KBONES*12];
  const int tid = threadIdx.x;
  for (int i = tid; i < KBONES*12; i += 256) rotL[i] = rotw[i];
  __syncthreads();
  const int n = blockIdx.x * 256 + tid;
  if (n >= N) return;

  const f32x4* lg = reinterpret_cast<const f32x4*>(logits + (size_t)n * KBONES);

  float ssum = 0.f;
  #pragma unroll 4
  for (int i = 0; i < 16; ++i) {
    const f32x4 z = lg[i];
    ssum += __expf(z[0]) + __expf(z[1]) + __expf(z[2]) + __expf(z[3]);
  }
  const float inv = 1.f / ssum;

  float M0=0.f,M1=0.f,M2=0.f,M3=0.f,M4=0.f,M5=0.f,M6=0.f,M7=0.f,M8=0.f;
  float tb0=0.f, tb1=0.f, tb2=0.f;
  unsigned char* xr = Xg + (size_t)n * KP1;
  #pragma unroll 1
  for (int cp = 0; cp < 4; ++cp) {
    u64t pk2[2];
    #pragma unroll
    for (int q = 0; q < 2; ++q) {
      const int c = cp*2 + q;
      const f32x4 za = lg[2*c];
      const f32x4 zb = lg[2*c+1];
      float w8[8];
      #pragma unroll
      for (int j = 0; j < 8; ++j) {
        const float zz = (j < 4) ? za[j] : zb[j-4];
        const float w = __expf(zz) * inv;
        w8[j] = w;
        const f32x4 r0 = *reinterpret_cast<const f32x4*>(&rotL[(c*8+j)*12]);
        const f32x4 r1 = *reinterpret_cast<const f32x4*>(&rotL[(c*8+j)*12+4]);
        const f32x4 r2 = *reinterpret_cast<const f32x4*>(&rotL[(c*8+j)*12+8]);
        M0+=w*r0[0]; M1+=w*r0[1]; M2+=w*r0[2];
        M3+=w*r0[3]; M4+=w*r1[0]; M5+=w*r1[1];
        M6+=w*r1[2]; M7+=w*r1[3]; M8+=w*r2[0];
        tb0+=w*r2[1]; tb1+=w*r2[2]; tb2+=w*r2[3];
      }
      pk2[q] = (u64t)cvt2fp8(w8[0], w8[1])
             | ((u64t)cvt2fp8(w8[2], w8[3]) << 16)
             | ((u64t)cvt2fp8(w8[4], w8[5]) << 32)
             | ((u64t)cvt2fp8(w8[6], w8[7]) << 48);
    }
    l64x2 chunk = { (long)pk2[0], (long)pk2[1] };
    *reinterpret_cast<l64x2*>(xr + cp*16) = chunk;
  }

  float M[9] = {M0,M1,M2,M3,M4,M5,M6,M7,M8};
  const float vx = verts[(size_t)n*3+0], vy = verts[(size_t)n*3+1], vz = verts[(size_t)n*3+2];
  const float p0 = M[0]*vx + M[1]*vy + M[2]*vz;   // Mv = skinned - t_b
  const float p1 = M[3]*vx + M[4]*vy + M[5]*vz;
  const float p2 = M[6]*vx + M[7]*vy + M[8]*vz;
  float R[9];
  polar_rotation(M, R);
  // local_p = R^T (Mv)
  const float lp0 = R[0]*p0 + R[3]*p1 + R[6]*p2;
  const float lp1 = R[1]*p0 + R[4]*p1 + R[7]*p2;
  const float lp2 = R[2]*p0 + R[5]*p1 + R[8]*p2;
  const u64t t8 = (u64t)cvt2fp8(lp0, lp1) | ((u64t)cvt2fp8(lp2, 0.f) << 16);
  l64x2 tail0 = { (long)t8, 0 };
  l64x2 zz2   = { 0, 0 };
  *reinterpret_cast<l64x2*>(xr + 64) = tail0;
  *reinterpret_cast<l64x2*>(xr + 80) = zz2;

  const float s0 = p0 + tb0, s1 = p1 + tb1, s2 = p2 + tb2;
  f32x4 rb0 = {R[0], R[1], R[2], R[3]};
  f32x4 rb1 = {R[4], R[5], R[6], R[7]};
  f32x4 rb2 = {R[8], s0, s1, s2};
  float* rr = RbS + (size_t)n * 12;
  *reinterpret_cast<f32x4*>(rr)     = rb0;
  *reinterpret_cast<f32x4*>(rr + 4) = rb1;
  *reinterpret_cast<f32x4*>(rr + 8) = rb2;

  const size_t o = (size_t)N*3 + (size_t)n*3;
  out[o+0] = s0; out[o+1] = s1; out[o+2] = s2;
}

// ---------------- kernel 3: MLP fp8 MFMA, C[h][n], in-place (r14) + unroll 4 ----------------
// r15 ping-pong was neutral -> barriers are not the binding term; the K-loop is.
// unroll 4 doubles in-flight W loads (8 a-frags, 16 VGPRs) to cover ~200cyc L2
// latency against ~155cyc MFMA/pair. Register cap (512,4) unchanged (r14-proven);
// WRITE_SIZE is the spill tripwire.
__global__ __launch_bounds__(512, 4) void mlp_kernel(
    const unsigned char* __restrict__ Xg,
    const unsigned char* __restrict__ W1f,
    const unsigned char* __restrict__ W2f,
    const unsigned char* __restrict__ W3f,
    const unsigned char* __restrict__ W4f,
    const float* __restrict__ b1p, const float* __restrict__ b2p,
    const float* __restrict__ b3p, const float* __restrict__ b4p,
    const float* __restrict__ RbS,
    float* __restrict__ out, int N) {

  __shared__ __align__(16) unsigned char Hs[BM][HSTB];  // 33792 B
  __shared__ float dL[BM][4];                           // 2048 B

  const int tid = threadIdx.x;
  const int vbase = blockIdx.x * BM;

  // stage X tile: 128 rows x 96 B = 768 16B chunks (zero-fill rows >= N)
  #pragma unroll
  for (int it = 0; it < 2; ++it) {
    const int c = tid + it*512;
    if (c < 768) {
      const int r = c / 6, cc = c % 6;
      s16x8 v = {0,0,0,0,0,0,0,0};
      if (vbase + r < N)
        v = __builtin_nontemporal_load(
              reinterpret_cast<const s16x8*>(Xg + (size_t)(vbase + r)*KP1 + cc*16));
      *reinterpret_cast<s16x8*>(&Hs[r][cc*16]) = v;
    }
  }
  __syncthreads();

  const int wave = tid >> 6;          // owns h rows [wave*32, wave*32+32)
  const int lane = tid & 63;
  const int lrow = lane & 15;
  const int hq   = lane >> 4;
  const int lkof = hq * 8;            // K offset in bytes (fp8)
  const int hb   = wave * 32;
  const f32x4 zf = {0.f,0.f,0.f,0.f};

  f32x4 acc[2][8];                    // [h-subtile t][vertex-subtile v]

#define EPI(A, T, V)                                                            \
  {                                                                             \
    const unsigned int p01 = cvt2fp8(fmaxf((A)[0],0.f), fmaxf((A)[1],0.f));     \
    const unsigned int p23 = cvt2fp8(fmaxf((A)[2],0.f), fmaxf((A)[3],0.f));     \
    *reinterpret_cast<unsigned int*>(&Hs[(V)*16 + lrow][hb + (T)*16 + hq*4])    \
        = p01 | (p23 << 16);                                                    \
  }

  // ---- layer 1: K=96 ----
  #pragma unroll
  for (int t = 0; t < 2; ++t) {
    const f32x4 bias = *reinterpret_cast<const f32x4*>(b1p + hb + t*16 + hq*4);
    #pragma unroll
    for (int v = 0; v < 8; ++v) acc[t][v] = bias;
  }
  #pragma unroll 2
  for (int ks = 0; ks < 3; ++ks) {
    const int kb = ks*32 + lkof;
    const long a0 = *reinterpret_cast<const long*>(W1f + (size_t)(hb +      lrow) * KP1 + kb);
    const long a1 = *reinterpret_cast<const long*>(W1f + (size_t)(hb + 16 + lrow) * KP1 + kb);
    #pragma unroll
    for (int v = 0; v < 8; ++v) {
      const long b = *reinterpret_cast<const long*>(&Hs[v*16 + lrow][kb]);
      acc[0][v] = __builtin_amdgcn_mfma_f32_16x16x32_fp8_fp8(a0, b, acc[0][v], 0, 0, 0);
      acc[1][v] = __builtin_amdgcn_mfma_f32_16x16x32_fp8_fp8(a1, b, acc[1][v], 0, 0, 0);
    }
  }
  __syncthreads();   // all X reads done before H1 overwrites
  #pragma unroll
  for (int t = 0; t < 2; ++t)
    #pragma unroll
    for (int v = 0; v < 8; ++v) EPI(acc[t][v], t, v)
  __syncthreads();

  // ---- layers 2 and 3: K=256 ----
  for (int layer = 0; layer < 2; ++layer) {
    const unsigned char* Wf = (layer == 0) ? W2f : W3f;
    const float* bp = (layer == 0) ? b2p : b3p;
    #pragma unroll
    for (int t = 0; t < 2; ++t) {
      const f32x4 bias = *reinterpret_cast<const f32x4*>(bp + hb + t*16 + hq*4);
      #pragma unroll
      for (int v = 0; v < 8; ++v) acc[t][v] = bias;
    }
    #pragma unroll 4
    for (int ks = 0; ks < 8; ++ks) {
      const int kb = ks*32 + lkof;
      const long a0 = *reinterpret_cast<const long*>(Wf + (size_t)(hb +      lrow) * HDIM + kb);
      const long a1 = *reinterpret_cast<const long*>(Wf + (size_t)(hb + 16 + lrow) * HDIM + kb);
      #pragma unroll
      for (int v = 0; v < 8; ++v) {
        const long b = *reinterpret_cast<const long*>(&Hs[v*16 + lrow][kb]);
        acc[0][v] = __builtin_amdgcn_mfma_f32_16x16x32_fp8_fp8(a0, b, acc[0][v], 0, 0, 0);
        acc[1][v] = __builtin_amdgcn_mfma_f32_16x16x32_fp8_fp8(a1, b, acc[1][v], 0, 0, 0);
      }
    }
    __syncthreads();
    #pragma unroll
    for (int t = 0; t < 2; ++t)
      #pragma unroll
      for (int v = 0; v < 8; ++v) EPI(acc[t][v], t, v)
    __syncthreads();
  }
#undef EPI

  // ---- layer 4 (256 -> 3, padded to 16): wave w owns vertices w*16+lrow ----
  {
    f32x4 a4 = zf;
    #pragma unroll 4
    for (int ks = 0; ks < 8; ++ks) {
      const int kb = ks*32 + lkof;
      const long af = *reinterpret_cast<const long*>(W4f + (size_t)lrow * HDIM + kb);
      const long b  = *reinterpret_cast<const long*>(&Hs[wave*16 + lrow][kb]);
      a4 = __builtin_amdgcn_mfma_f32_16x16x32_fp8_fp8(af, b, a4, 0, 0, 0);
    }
    // C[j][n]: lane holds rows j=(hq*4..+3) of vertex wave*16+lrow; j<3 at hq==0
    if (hq == 0) {
      dL[wave*16 + lrow][0] = a4[0] + b4p[0];
      dL[wave*16 + lrow][1] = a4[1] + b4p[1];
      dL[wave*16 + lrow][2] = a4[2] + b4p[2];
    }
  }
  __syncthreads();

  // ---- final: tanh, rotate back, write posed + delta ----
  if (tid < BM) {
    const int n = vbase + tid;
    if (n < N) {
      const float* rr = RbS + (size_t)n * 12;
      f32x4 q0 = __builtin_nontemporal_load(reinterpret_cast<const f32x4*>(rr));
      f32x4 q1 = __builtin_nontemporal_load(reinterpret_cast<const f32x4*>(rr + 4));
      f32x4 q2 = __builtin_nontemporal_load(reinterpret_cast<const f32x4*>(rr + 8));
      const float dl0 = 0.02f * tanhf(dL[tid][0]);
      const float dl1 = 0.02f * tanhf(dL[tid][1]);
      const float dl2 = 0.02f * tanhf(dL[tid][2]);
      const float dw0 = q0[0]*dl0 + q0[1]*dl1 + q0[2]*dl2;
      const float dw1 = q0[3]*dl0 + q1[0]*dl1 + q1[1]*dl2;
      const float dw2 = q1[2]*dl0 + q1[3]*dl1 + q2[0]*dl2;
      const float s0 = q2[1], s1 = q2[2], s2 = q2[3];
      const size_t o  = (size_t)n * 3;
      const size_t NB = (size_t)N * 3;
      out[o+0]      = s0 + dw0; out[o+1]      = s1 + dw1; out[o+2]      = s2 + dw2;
      out[2*NB+o+0] = dw0;      out[2*NB+o+1] = dw1;      out[2*NB+o+2] = dw2;
    }
  }
}

// ---------------- fallback: fused kernel (small workspace), bf16 ----------------
__global__ __launch_bounds__(512, 2) void deform_fused_kernel(
    const float* __restrict__ verts,
    const float* __restrict__ logits,
    const float* __restrict__ rotw,
    const unsigned short* __restrict__ W1t,
    const unsigned short* __restrict__ W2t,
    const unsigned short* __restrict__ W3t,
    const float* __restrict__ b1p, const float* __restrict__ b2p, const float* __restrict__ b3p,
    const float* __restrict__ W4, const float* __restrict__ b4p,
    float* __restrict__ out, int N) {

  __shared__ __align__(16) unsigned short Hbuf[BM][HST];
  __shared__ float rotL[KBONES*12];
  __shared__ float RbL[BM][9];
  __shared__ float skL[BM][3];

  const int tid = threadIdx.x;
  for (int i = tid; i < KBONES*12; i += 512) rotL[i] = rotw[i];
  __syncthreads();

  const int vbase = blockIdx.x * BM;

  if (tid < BM) {
    const int n = vbase + tid;
    if (n < N) {
      const float* lgp = logits + (size_t)n * KBONES;
      float ssum = 0.f;
      #pragma unroll 1
      for (int i = 0; i < 16; ++i) {
        const f32x4 z = reinterpret_cast<const f32x4*>(lgp)[i];
        ssum += __expf(z[0]) + __expf(z[1]) + __expf(z[2]) + __expf(z[3]);
      }
      float inv = 1.f / ssum;
      float M[9] = {0,0,0,0,0,0,0,0,0};
      float tb0 = 0.f, tb1 = 0.f, tb2 = 0.f;
      #pragma unroll 1
      for (int c = 0; c < 8; ++c) {
        const f32x4 za = reinterpret_cast<const f32x4*>(lgp)[2*c];
        const f32x4 zb = reinterpret_cast<const f32x4*>(lgp)[2*c+1];
        s16x8 sv;
        #pragma unroll
        for (int j = 0; j < 8; ++j) {
          const float zz = (j < 4) ? za[j] : zb[j-4];
          const float w = __expf(zz) * inv;
          sv[j] = (short)f2bf(w);
          const float* rk = &rotL[(c*8+j)*12];
          M[0] += w*rk[0]; M[1] += w*rk[1]; M[2] += w*rk[2];
          M[3] += w*rk[3]; M[4] += w*rk[4]; M[5] += w*rk[5];
          M[6] += w*rk[6]; M[7] += w*rk[7]; M[8] += w*rk[8];
          tb0 += w*rk[9]; tb1 += w*rk[10]; tb2 += w*rk[11];
        }
        *reinterpret_cast<s16x8*>(&Hbuf[tid][c*8]) = sv;
      }
      float vx = verts[(size_t)n*3+0], vy = verts[(size_t)n*3+1], vz = verts[(size_t)n*3+2];
      float p0 = M[0]*vx + M[1]*vy + M[2]*vz;
      float p1 = M[3]*vx + M[4]*vy + M[5]*vz;
      float p2 = M[6]*vx + M[7]*vy + M[8]*vz;
      float R[9];
      polar_rotation(M, R);
      const s16x8 z8 = {0,0,0,0,0,0,0,0};
      #pragma unroll
      for (int i = 8; i < 12; ++i) *reinterpret_cast<s16x8*>(&Hbuf[tid][i*8]) = z8;
      Hbuf[tid][64] = f2bf(R[0]*p0 + R[3]*p1 + R[6]*p2);
      Hbuf[tid][65] = f2bf(R[1]*p0 + R[4]*p1 + R[7]*p2);
      Hbuf[tid][66] = f2bf(R[2]*p0 + R[5]*p1 + R[8]*p2);
      #pragma unroll
      for (int e = 0; e < 9; ++e) RbL[tid][e] = R[e];
      skL[tid][0] = p0 + tb0; skL[tid][1] = p1 + tb1; skL[tid][2] = p2 + tb2;
    } else {
      const s16x8 z8 = {0,0,0,0,0,0,0,0};
      #pragma unroll
      for (int i = 0; i < 12; ++i) *reinterpret_cast<s16x8*>(&Hbuf[tid][i*8]) = z8;
    }
  }
  __syncthreads();

  const int wave = tid >> 6;
  const int lane = tid & 63;
  const int lrow = lane & 15;
  const int lkof = (lane >> 4) * 8;
  const int c0 = (wave*2+0)*16 + lrow;
  const int c1 = (wave*2+1)*16 + lrow;
  const f32x4 zf = {0.f,0.f,0.f,0.f};
  f32x4 acc[8][2];

  #pragma unroll
  for (int mt = 0; mt < 8; ++mt) { acc[mt][0] = zf; acc[mt][1] = zf; }
  #pragma unroll
  for (int ks = 0; ks < 3; ++ks) {
    const int kb = ks*32 + lkof;
    s16x8 bf0 = *reinterpret_cast<const s16x8*>(W1t + (size_t)c0 * KP1 + kb);
    s16x8 bf1 = *reinterpret_cast<const s16x8*>(W1t + (size_t)c1 * KP1 + kb);
    #pragma unroll
    for (int mt = 0; mt < 8; ++mt) {
      s16x8 af = *reinterpret_cast<const s16x8*>(&Hbuf[mt*16 + lrow][kb]);
      acc[mt][0] = __builtin_amdgcn_mfma_f32_16x16x32_bf16(af, bf0, acc[mt][0], 0, 0, 0);
      acc[mt][1] = __builtin_amdgcn_mfma_f32_16x16x32_bf16(af, bf1, acc[mt][1], 0, 0, 0);
    }
  }
  __syncthreads();
  {
    const float bb0 = b1p[c0], bb1 = b1p[c1];
    #pragma unroll
    for (int mt = 0; mt < 8; ++mt) {
      const int rbase = mt*16 + (lane>>4)*4;
      #pragma unroll
      for (int r = 0; r < 4; ++r) {
        Hbuf[rbase+r][c0] = f2bf(fmaxf(acc[mt][0][r] + bb0, 0.f));
        Hbuf[rbase+r][c1] = f2bf(fmaxf(acc[mt][1][r] + bb1, 0.f));
      }
    }
  }
  __syncthreads();

  for (int layer = 0; layer < 2; ++layer) {
    const unsigned short* Wt = (layer == 0) ? W2t : W3t;
    const float* bp = (layer == 0) ? b2p : b3p;
    #pragma unroll
    for (int mt = 0; mt < 8; ++mt) { acc[mt][0] = zf; acc[mt][1] = zf; }
    #pragma unroll
    for (int ks = 0; ks < 8; ++ks) {
      const int kb = ks*32 + lkof;
      s16x8 bf0 = *reinterpret_cast<const s16x8*>(Wt + (size_t)c0 * HDIM + kb);
      s16x8 bf1 = *reinterpret_cast<const s16x8*>(Wt + (size_t)c1 * HDIM + kb);
      #pragma unroll
      for (int mt = 0; mt < 8; ++mt) {
        s16x8 af = *reinterpret_cast<const s16x8*>(&Hbuf[mt*16 + lrow][kb]);
        acc[mt][0] = __builtin_amdgcn_mfma_f32_16x16x32_bf16(af, bf0, acc[mt][0], 0, 0, 0);
        acc[mt][1] = __builtin_amdgcn_mfma_f32_16x16x32_bf16(af, bf1, acc[mt][1], 0, 0, 0);
      }
    }
    __syncthreads();
    const float bb0 = bp[c0], bb1 = bp[c1];
    #pragma unroll
    for (int mt = 0; mt < 8; ++mt) {
      const int rbase = mt*16 + (lane>>4)*4;
      #pragma unroll
      for (int r = 0; r < 4; ++r) {
        Hbuf[rbase+r][c0] = f2bf(fmaxf(acc[mt][0][r] + bb0, 0.f));
        Hbuf[rbase+r][c1] = f2bf(fmaxf(acc[mt][1][r] + bb1, 0.f));
      }
    }
    __syncthreads();
  }

  if (tid < BM) {
    const int n = vbase + tid;
    if (n < N) {
      float d0 = b4p[0], d1 = b4p[1], d2 = b4p[2];
      const s16x8* hp = reinterpret_cast<const s16x8*>(&Hbuf[tid][0]);
      #pragma unroll
      for (int i = 0; i < 32; ++i) {
        s16x8 h8 = hp[i];
        #pragma unroll
        for (int j = 0; j < 8; ++j) {
          const float h = bf2f((unsigned short)h8[j]);
          const int c = i*8 + j;
          d0 += h * W4[c*3+0];
          d1 += h * W4[c*3+1];
          d2 += h * W4[c*3+2];
        }
      }
      const float dl0 = 0.02f * tanhf(d0);
      const float dl1 = 0.02f * tanhf(d1);
      const float dl2 = 0.02f * tanhf(d2);
      float R[9];
      #pragma unroll
      for (int e = 0; e < 9; ++e) R[e] = RbL[tid][e];
      const float dw0 = R[0]*dl0 + R[1]*dl1 + R[2]*dl2;
      const float dw1 = R[3]*dl0 + R[4]*dl1 + R[5]*dl2;
      const float dw2 = R[6]*dl0 + R[7]*dl1 + R[8]*dl2;
      const float s0 = skL[tid][0], s1 = skL[tid][1], s2 = skL[tid][2];
      const size_t o  = (size_t)n * 3;
      const size_t NB = (size_t)N * 3;
      out[o+0]      = s0 + dw0; out[o+1]      = s1 + dw1; out[o+2]      = s2 + dw2;
      out[NB+o+0]   = s0;       out[NB+o+1]   = s1;       out[NB+o+2]   = s2;
      out[2*NB+o+0] = dw0;      out[2*NB+o+1] = dw1;      out[2*NB+o+2] = dw2;
    }
  }
}

extern "C" void kernel_launch(void* const* d_in, const int* in_sizes, int n_in,
                              void* d_out, int out_size, void* d_ws, size_t ws_size,
                              hipStream_t stream) {
  const float* verts  = (const float*)d_in[0];
  const float* logits = (const float*)d_in[1];
  const float* rot6d  = (const float*)d_in[2];
  const float* trans  = (const float*)d_in[3];
  const float* W1 = (const float*)d_in[4];
  const float* b1 = (const float*)d_in[5];
  const float* W2 = (const float*)d_in[6];
  const float* b2 = (const float*)d_in[7];
  const float* W3 = (const float*)d_in[8];
  const float* b3 = (const float*)d_in[9];
  const float* W4 = (const float*)d_in[10];
  const float* b4 = (const float*)d_in[11];
  float* out = (float*)d_out;
  const int N = in_sizes[0] / 3;
  const size_t N128 = (((size_t)N + 127) / 128) * 128;

  char* ws = (char*)d_ws;
  const size_t o_rotw = 0;                             // 3072
  const size_t o_w1t  = 4096;                          // 49152 (bf16, fallback)
  const size_t o_w2t  = o_w1t + 49152;                 // 131072
  const size_t o_w3t  = o_w2t + 131072;                // 131072
  const size_t o_w1f  = o_w3t + 131072;                // 24576 (fp8)
  const size_t o_w2f  = o_w1f + 24576;                 // 65536
  const size_t o_w3f  = o_w2f + 65536;                 // 65536
  const size_t o_w4f  = o_w3f + 65536;                 // 4096
  const size_t o_rbs  = (o_w4f + 4096 + 255) & ~(size_t)255;   // N*48
  const size_t o_x    = (o_rbs + (size_t)N*48 + 255) & ~(size_t)255;
  const size_t need   = o_x + N128 * KP1;              // fp8 X: 96 B/row

  float*          rotw = (float*)(ws + o_rotw);
  unsigned short* W1t  = (unsigned short*)(ws + o_w1t);
  unsigned short* W2t  = (unsigned short*)(ws + o_w2t);
  unsigned short* W3t  = (unsigned short*)(ws + o_w3t);
  unsigned char*  W1f  = (unsigned char*)(ws + o_w1f);
  unsigned char*  W2f  = (unsigned char*)(ws + o_w2f);
  unsigned char*  W3f  = (unsigned char*)(ws + o_w3f);
  unsigned char*  W4f  = (unsigned char*)(ws + o_w4f);
  float*          RbS  = (float*)(ws + o_rbs);
  unsigned char*  Xg   = (unsigned char*)(ws + o_x);

  prep_kernel<<<128, 256, 0, stream>>>(rot6d, trans, W1, W2, W3, W4,
                                       rotw, W1t, W2t, W3t, W1f, W2f, W3f, W4f);

  if (ws_size >= need) {
    const int grid2 = (N + 255) / 256;
    vertex_kernel<<<grid2, 256, 0, stream>>>(verts, logits, rotw, Xg, RbS, out, N);
    const int grid3 = (int)(N128 / 128);
    mlp_kernel<<<grid3, 512, 0, stream>>>(Xg, W1f, W2f, W3f, W4f,
                                          b1, b2, b3, b4, RbS, out, N);
  } else {
    const int grid = (N + BM - 1) / BM;
    deform_fused_kernel<<<grid, 512, 0, stream>>>(verts, logits, rotw, W1t, W2t, W3t,
                                                  b1, b2, b3, W4, b4, out, N);
  }
}

// Round 17
// 276.385 us; speedup vs baseline: 1.1353x; 1.1353x over previous
//
#include <hip/hip_runtime.h>
#include <hip/hip_bf16.h>

typedef short  s16x8 __attribute__((ext_vector_type(8)));
typedef float  f32x4 __attribute__((ext_vector_type(4)));
typedef long   l64x2 __attribute__((ext_vector_type(2)));
typedef unsigned long long u64t;

#define KBONES 64
#define HDIM   256
#define KP1    96     // padded K for layer 1 (67 -> 96)
#define BM     128    // vertices per block (mlp kernel)
#define HST    264    // bf16 LDS row stride (fallback kernel)
#define HSTB   264    // fp8 LDS row stride in BYTES: 66 dw % 32 = 2 -> conflict-free b64 reads

__device__ __forceinline__ unsigned short f2bf(float f) {
  unsigned int u = __float_as_uint(f);
  u += 0x7FFFu + ((u >> 16) & 1u);       // RNE (finite values only here)
  return (unsigned short)(u >> 16);
}
__device__ __forceinline__ float bf2f(unsigned short u) {
  union { unsigned int i; float f; } x; x.i = ((unsigned int)u) << 16; return x.f;
}
// HW fp8 conversion: v_cvt_pk_fp8_f32 (OCP e4m3 on gfx950, RNE + saturate).
__device__ __forceinline__ unsigned int cvt2fp8(float a, float b) {
  return ((unsigned int)__builtin_amdgcn_cvt_pk_fp8_f32(a, b, 0, false)) & 0xFFFFu;
}
__device__ __forceinline__ unsigned char f2fp8(float f) {
  return (unsigned char)(cvt2fp8(f, 0.f) & 0xFFu);
}

// ---------------- prep: rotations + bf16 (fallback) + fp8 (main) weights ----------------
// rotw layout: [k][12] = {R row-major 0..8, t 9..11}
__global__ void prep_kernel(const float* __restrict__ rot6d,
                            const float* __restrict__ trans,
                            const float* __restrict__ W1,
                            const float* __restrict__ W2,
                            const float* __restrict__ W3,
                            const float* __restrict__ W4,
                            float* __restrict__ rotw,
                            unsigned short* __restrict__ W1t,
                            unsigned short* __restrict__ W2t,
                            unsigned short* __restrict__ W3t,
                            unsigned char* __restrict__ W1f,
                            unsigned char* __restrict__ W2f,
                            unsigned char* __restrict__ W3f,
                            unsigned char* __restrict__ W4f) {
  int tid = blockIdx.x * blockDim.x + threadIdx.x;
  int stride = gridDim.x * blockDim.x;
  if (tid < KBONES) {
    int k = tid;
    float a10 = rot6d[k*6+0], a11 = rot6d[k*6+1], a12 = rot6d[k*6+2];
    float a20 = rot6d[k*6+3], a21 = rot6d[k*6+4], a22 = rot6d[k*6+5];
    float n1 = fmaxf(sqrtf(a10*a10 + a11*a11 + a12*a12), 1e-12f);
    float b1x = a10/n1, b1y = a11/n1, b1z = a12/n1;
    float d  = b1x*a20 + b1y*a21 + b1z*a22;
    float c0 = a20 - d*b1x, c1 = a21 - d*b1y, c2 = a22 - d*b1z;
    float n2 = fmaxf(sqrtf(c0*c0 + c1*c1 + c2*c2), 1e-12f);
    float b2x = c0/n2, b2y = c1/n2, b2z = c2/n2;
    float b3x = b1y*b2z - b1z*b2y;
    float b3y = b1z*b2x - b1x*b2z;
    float b3z = b1x*b2y - b1y*b2x;
    rotw[k*12+0]=b1x; rotw[k*12+1]=b2x; rotw[k*12+2]=b3x;
    rotw[k*12+3]=b1y; rotw[k*12+4]=b2y; rotw[k*12+5]=b3y;
    rotw[k*12+6]=b1z; rotw[k*12+7]=b2z; rotw[k*12+8]=b3z;
    rotw[k*12+9]=trans[k*3+0]; rotw[k*12+10]=trans[k*3+1]; rotw[k*12+11]=trans[k*3+2];
  }
  // [h][kk]: kk 0..63 = w (W1 row 3+kk), 64..66 = local_p (W1 row kk-64), 67..95 = 0
  for (int i = tid; i < HDIM*KP1; i += stride) {
    int h = i / KP1, kk = i % KP1;
    float v = (kk < 64) ? W1[(size_t)(3+kk)*HDIM + h]
            : (kk < 67) ? W1[(size_t)(kk-64)*HDIM + h] : 0.f;
    W1t[i] = f2bf(v);
    W1f[i] = f2fp8(v);
  }
  for (int i = tid; i < HDIM*HDIM; i += stride) {
    int h2 = i / HDIM, h1 = i % HDIM;
    float v2 = W2[(size_t)h1*HDIM + h2];
    float v3 = W3[(size_t)h1*HDIM + h2];
    W2t[i] = f2bf(v2);  W2f[i] = f2fp8(v2);
    W3t[i] = f2bf(v3);  W3f[i] = f2fp8(v3);
  }
  // W4f[j][h], j padded 3->16
  for (int i = tid; i < 16*HDIM; i += stride) {
    int j = i / HDIM, h = i % HDIM;
    W4f[i] = (j < 3) ? f2fp8(W4[(size_t)h*3 + j]) : (unsigned char)0;
  }
}

// ---------------- per-vertex polar rotation (matches U diag(1,1,s) Vh) ----------------
__device__ __forceinline__ void polar_rotation(const float M[9], float R[9]) {
  float a00 = M[0]*M[0] + M[3]*M[3] + M[6]*M[6];
  float a01 = M[0]*M[1] + M[3]*M[4] + M[6]*M[7];
  float a02 = M[0]*M[2] + M[3]*M[5] + M[6]*M[8];
  float a11 = M[1]*M[1] + M[4]*M[4] + M[7]*M[7];
  float a12 = M[1]*M[2] + M[4]*M[5] + M[7]*M[8];
  float a22 = M[2]*M[2] + M[5]*M[5] + M[8]*M[8];
  float v00=1.f,v01=0.f,v02=0.f, v10=0.f,v11=1.f,v12=0.f, v20=0.f,v21=0.f,v22=1.f;

#define JROT(APP,AQQ,APQ,APR,AQR, VP0,VQ0, VP1,VQ1, VP2,VQ2)                     \
  {                                                                              \
    float apq = APQ;                                                             \
    if (fabsf(apq) > 1e-25f) {                                                   \
      float tau = (AQQ - APP) / (2.f * apq);                                     \
      float tt  = copysignf(1.f / (fabsf(tau) + sqrtf(1.f + tau*tau)), tau);     \
      float c   = 1.f / sqrtf(1.f + tt*tt);                                      \
      float s   = tt * c;                                                        \
      APP -= tt * apq; AQQ += tt * apq; APQ = 0.f;                               \
      float pr = APR, qr = AQR;                                                  \
      APR = c*pr - s*qr; AQR = s*pr + c*qr;                                      \
      float t0;                                                                  \
      t0 = VP0; VP0 = c*t0 - s*VQ0; VQ0 = s*t0 + c*VQ0;                          \
      t0 = VP1; VP1 = c*t0 - s*VQ1; VQ1 = s*t0 + c*VQ1;                          \
      t0 = VP2; VP2 = c*t0 - s*VQ2; VQ2 = s*t0 + c*VQ2;                          \
    }                                                                            \
  }

  #pragma unroll
  for (int sweep = 0; sweep < 5; ++sweep) {
    JROT(a00, a11, a01, a02, a12, v00,v01, v10,v11, v20,v21)
    JROT(a00, a22, a02, a01, a12, v00,v02, v10,v12, v20,v22)
    JROT(a11, a22, a12, a01, a02, v01,v02, v11,v12, v21,v22)
  }
#undef JROT

  float l0=a00, l1=a11, l2=a22;
  float e0x=v00,e0y=v10,e0z=v20;
  float e1x=v01,e1y=v11,e1z=v21;
  float e2x=v02,e2y=v12,e2z=v22;
  float tf;
  if (l0 < l1) { tf=l0;l0=l1;l1=tf; tf=e0x;e0x=e1x;e1x=tf; tf=e0y;e0y=e1y;e1y=tf; tf=e0z;e0z=e1z;e1z=tf; }
  if (l0 < l2) { tf=l0;l0=l2;l2=tf; tf=e0x;e0x=e2x;e2x=tf; tf=e0y;e0y=e2y;e2y=tf; tf=e0z;e0z=e2z;e2z=tf; }
  if (l1 < l2) { tf=l1;l1=l2;l2=tf; tf=e1x;e1x=e2x;e2x=tf; tf=e1y;e1y=e2y;e2y=tf; tf=e1z;e1z=e2z;e2z=tf; }

  float u1x = M[0]*e0x + M[1]*e0y + M[2]*e0z;
  float u1y = M[3]*e0x + M[4]*e0y + M[5]*e0z;
  float u1z = M[6]*e0x + M[7]*e0y + M[8]*e0z;
  float i1 = 1.f / fmaxf(sqrtf(u1x*u1x + u1y*u1y + u1z*u1z), 1e-25f);
  u1x*=i1; u1y*=i1; u1z*=i1;
  float u2x = M[0]*e1x + M[1]*e1y + M[2]*e1z;
  float u2y = M[3]*e1x + M[4]*e1y + M[5]*e1z;
  float u2z = M[6]*e1x + M[7]*e1y + M[8]*e1z;
  float dd = u1x*u2x + u1y*u2y + u1z*u2z;
  u2x -= dd*u1x; u2y -= dd*u1y; u2z -= dd*u1z;
  float i2 = 1.f / fmaxf(sqrtf(u2x*u2x + u2y*u2y + u2z*u2z), 1e-25f);
  u2x*=i2; u2y*=i2; u2z*=i2;
  float u3x = u1y*u2z - u1z*u2y;
  float u3y = u1z*u2x - u1x*u2z;
  float u3z = u1x*u2y - u1y*u2x;
  float w2x = e0y*e1z - e0z*e1y;
  float w2y = e0z*e1x - e0x*e1z;
  float w2z = e0x*e1y - e0y*e1x;
  R[0] = u1x*e0x + u2x*e1x + u3x*w2x;
  R[1] = u1x*e0y + u2x*e1y + u3x*w2y;
  R[2] = u1x*e0z + u2x*e1z + u3x*w2z;
  R[3] = u1y*e0x + u2y*e1x + u3y*w2x;
  R[4] = u1y*e0y + u2y*e1y + u3y*w2y;
  R[5] = u1y*e0z + u2y*e1z + u3y*w2z;
  R[6] = u1z*e0x + u2z*e1x + u3z*w2x;
  R[7] = u1z*e0y + u2z*e1y + u3z*w2y;
  R[8] = u1z*e0z + u2z*e1z + u3z*w2z;
}

// ---------------- kernel 2: one thread per vertex (softmax, blend, SVD) ----------------
// Pass-1 unroll 4 (ILP for HBM latency) — proven r13/r14.
__global__ __launch_bounds__(256) void vertex_kernel(
                              const float* __restrict__ verts,
                              const float* __restrict__ logits,
                              const float* __restrict__ rotw,
                              unsigned char* __restrict__ Xg,
                              float* __restrict__ RbS,
                              float* __restrict__ out, int N) {
  __shared__ float rotL[KBONES*12];
  const int tid = threadIdx.x;
  for (int i = tid; i < KBONES*12; i += 256) rotL[i] = rotw[i];
  __syncthreads();
  const int n = blockIdx.x * 256 + tid;
  if (n >= N) return;

  const f32x4* lg = reinterpret_cast<const f32x4*>(logits + (size_t)n * KBONES);

  float ssum = 0.f;
  #pragma unroll 4
  for (int i = 0; i < 16; ++i) {
    const f32x4 z = lg[i];
    ssum += __expf(z[0]) + __expf(z[1]) + __expf(z[2]) + __expf(z[3]);
  }
  const float inv = 1.f / ssum;

  float M0=0.f,M1=0.f,M2=0.f,M3=0.f,M4=0.f,M5=0.f,M6=0.f,M7=0.f,M8=0.f;
  float tb0=0.f, tb1=0.f, tb2=0.f;
  unsigned char* xr = Xg + (size_t)n * KP1;
  #pragma unroll 1
  for (int cp = 0; cp < 4; ++cp) {
    u64t pk2[2];
    #pragma unroll
    for (int q = 0; q < 2; ++q) {
      const int c = cp*2 + q;
      const f32x4 za = lg[2*c];
      const f32x4 zb = lg[2*c+1];
      float w8[8];
      #pragma unroll
      for (int j = 0; j < 8; ++j) {
        const float zz = (j < 4) ? za[j] : zb[j-4];
        const float w = __expf(zz) * inv;
        w8[j] = w;
        const f32x4 r0 = *reinterpret_cast<const f32x4*>(&rotL[(c*8+j)*12]);
        const f32x4 r1 = *reinterpret_cast<const f32x4*>(&rotL[(c*8+j)*12+4]);
        const f32x4 r2 = *reinterpret_cast<const f32x4*>(&rotL[(c*8+j)*12+8]);
        M0+=w*r0[0]; M1+=w*r0[1]; M2+=w*r0[2];
        M3+=w*r0[3]; M4+=w*r1[0]; M5+=w*r1[1];
        M6+=w*r1[2]; M7+=w*r1[3]; M8+=w*r2[0];
        tb0+=w*r2[1]; tb1+=w*r2[2]; tb2+=w*r2[3];
      }
      pk2[q] = (u64t)cvt2fp8(w8[0], w8[1])
             | ((u64t)cvt2fp8(w8[2], w8[3]) << 16)
             | ((u64t)cvt2fp8(w8[4], w8[5]) << 32)
             | ((u64t)cvt2fp8(w8[6], w8[7]) << 48);
    }
    l64x2 chunk = { (long)pk2[0], (long)pk2[1] };
    *reinterpret_cast<l64x2*>(xr + cp*16) = chunk;
  }

  float M[9] = {M0,M1,M2,M3,M4,M5,M6,M7,M8};
  const float vx = verts[(size_t)n*3+0], vy = verts[(size_t)n*3+1], vz = verts[(size_t)n*3+2];
  const float p0 = M[0]*vx + M[1]*vy + M[2]*vz;   // Mv = skinned - t_b
  const float p1 = M[3]*vx + M[4]*vy + M[5]*vz;
  const float p2 = M[6]*vx + M[7]*vy + M[8]*vz;
  float R[9];
  polar_rotation(M, R);
  // local_p = R^T (Mv)
  const float lp0 = R[0]*p0 + R[3]*p1 + R[6]*p2;
  const float lp1 = R[1]*p0 + R[4]*p1 + R[7]*p2;
  const float lp2 = R[2]*p0 + R[5]*p1 + R[8]*p2;
  const u64t t8 = (u64t)cvt2fp8(lp0, lp1) | ((u64t)cvt2fp8(lp2, 0.f) << 16);
  l64x2 tail0 = { (long)t8, 0 };
  l64x2 zz2   = { 0, 0 };
  *reinterpret_cast<l64x2*>(xr + 64) = tail0;
  *reinterpret_cast<l64x2*>(xr + 80) = zz2;

  const float s0 = p0 + tb0, s1 = p1 + tb1, s2 = p2 + tb2;
  f32x4 rb0 = {R[0], R[1], R[2], R[3]};
  f32x4 rb1 = {R[4], R[5], R[6], R[7]};
  f32x4 rb2 = {R[8], s0, s1, s2};
  float* rr = RbS + (size_t)n * 12;
  *reinterpret_cast<f32x4*>(rr)     = rb0;
  *reinterpret_cast<f32x4*>(rr + 4) = rb1;
  *reinterpret_cast<f32x4*>(rr + 8) = rb2;

  const size_t o = (size_t)N*3 + (size_t)n*3;
  out[o+0] = s0; out[o+1] = s1; out[o+2] = s2;
}

// ---------------- kernel 3: MLP fp8 MFMA, C[h][n], register-capped [r14 best: 194.8 us] ----
// Ledger: unroll 2 = 194.8 us (this); unroll 4 = spill (r16, WRITE 156 MB);
// ping-pong barriers = neutral (r15). The 2-barrier lockstep structure ceiling
// is ~195 us @ MfmaUtil ~34%; past it requires the 8-phase counted-vmcnt
// rewrite (not attempted headlessly). (512,4) caps regs at 128; the ~4-reg
// deficit remats instead of spilling.
__global__ __launch_bounds__(512, 4) void mlp_kernel(
    const unsigned char* __restrict__ Xg,
    const unsigned char* __restrict__ W1f,
    const unsigned char* __restrict__ W2f,
    const unsigned char* __restrict__ W3f,
    const unsigned char* __restrict__ W4f,
    const float* __restrict__ b1p, const float* __restrict__ b2p,
    const float* __restrict__ b3p, const float* __restrict__ b4p,
    const float* __restrict__ RbS,
    float* __restrict__ out, int N) {

  __shared__ __align__(16) unsigned char Hs[BM][HSTB];  // 33792 B
  __shared__ float dL[BM][4];                           // 2048 B

  const int tid = threadIdx.x;
  const int vbase = blockIdx.x * BM;

  // stage X tile: 128 rows x 96 B = 768 16B chunks (zero-fill rows >= N)
  #pragma unroll
  for (int it = 0; it < 2; ++it) {
    const int c = tid + it*512;
    if (c < 768) {
      const int r = c / 6, cc = c % 6;
      s16x8 v = {0,0,0,0,0,0,0,0};
      if (vbase + r < N)
        v = __builtin_nontemporal_load(
              reinterpret_cast<const s16x8*>(Xg + (size_t)(vbase + r)*KP1 + cc*16));
      *reinterpret_cast<s16x8*>(&Hs[r][cc*16]) = v;
    }
  }
  __syncthreads();

  const int wave = tid >> 6;          // owns h rows [wave*32, wave*32+32)
  const int lane = tid & 63;
  const int lrow = lane & 15;
  const int hq   = lane >> 4;
  const int lkof = hq * 8;            // K offset in bytes (fp8)
  const int hb   = wave * 32;
  const f32x4 zf = {0.f,0.f,0.f,0.f};

  f32x4 acc[2][8];                    // [h-subtile t][vertex-subtile v]

#define EPI(A, T, V)                                                            \
  {                                                                             \
    const unsigned int p01 = cvt2fp8(fmaxf((A)[0],0.f), fmaxf((A)[1],0.f));     \
    const unsigned int p23 = cvt2fp8(fmaxf((A)[2],0.f), fmaxf((A)[3],0.f));     \
    *reinterpret_cast<unsigned int*>(&Hs[(V)*16 + lrow][hb + (T)*16 + hq*4])    \
        = p01 | (p23 << 16);                                                    \
  }

  // ---- layer 1: K=96 ----
  #pragma unroll
  for (int t = 0; t < 2; ++t) {
    const f32x4 bias = *reinterpret_cast<const f32x4*>(b1p + hb + t*16 + hq*4);
    #pragma unroll
    for (int v = 0; v < 8; ++v) acc[t][v] = bias;
  }
  #pragma unroll 2
  for (int ks = 0; ks < 3; ++ks) {
    const int kb = ks*32 + lkof;
    const long a0 = *reinterpret_cast<const long*>(W1f + (size_t)(hb +      lrow) * KP1 + kb);
    const long a1 = *reinterpret_cast<const long*>(W1f + (size_t)(hb + 16 + lrow) * KP1 + kb);
    #pragma unroll
    for (int v = 0; v < 8; ++v) {
      const long b = *reinterpret_cast<const long*>(&Hs[v*16 + lrow][kb]);
      acc[0][v] = __builtin_amdgcn_mfma_f32_16x16x32_fp8_fp8(a0, b, acc[0][v], 0, 0, 0);
      acc[1][v] = __builtin_amdgcn_mfma_f32_16x16x32_fp8_fp8(a1, b, acc[1][v], 0, 0, 0);
    }
  }
  __syncthreads();   // all X reads done before H1 overwrites
  #pragma unroll
  for (int t = 0; t < 2; ++t)
    #pragma unroll
    for (int v = 0; v < 8; ++v) EPI(acc[t][v], t, v)
  __syncthreads();

  // ---- layers 2 and 3: K=256 ----
  for (int layer = 0; layer < 2; ++layer) {
    const unsigned char* Wf = (layer == 0) ? W2f : W3f;
    const float* bp = (layer == 0) ? b2p : b3p;
    #pragma unroll
    for (int t = 0; t < 2; ++t) {
      const f32x4 bias = *reinterpret_cast<const f32x4*>(bp + hb + t*16 + hq*4);
      #pragma unroll
      for (int v = 0; v < 8; ++v) acc[t][v] = bias;
    }
    #pragma unroll 2
    for (int ks = 0; ks < 8; ++ks) {
      const int kb = ks*32 + lkof;
      const long a0 = *reinterpret_cast<const long*>(Wf + (size_t)(hb +      lrow) * HDIM + kb);
      const long a1 = *reinterpret_cast<const long*>(Wf + (size_t)(hb + 16 + lrow) * HDIM + kb);
      #pragma unroll
      for (int v = 0; v < 8; ++v) {
        const long b = *reinterpret_cast<const long*>(&Hs[v*16 + lrow][kb]);
        acc[0][v] = __builtin_amdgcn_mfma_f32_16x16x32_fp8_fp8(a0, b, acc[0][v], 0, 0, 0);
        acc[1][v] = __builtin_amdgcn_mfma_f32_16x16x32_fp8_fp8(a1, b, acc[1][v], 0, 0, 0);
      }
    }
    __syncthreads();
    #pragma unroll
    for (int t = 0; t < 2; ++t)
      #pragma unroll
      for (int v = 0; v < 8; ++v) EPI(acc[t][v], t, v)
    __syncthreads();
  }
#undef EPI

  // ---- layer 4 (256 -> 3, padded to 16): wave w owns vertices w*16+lrow ----
  {
    f32x4 a4 = zf;
    #pragma unroll 2
    for (int ks = 0; ks < 8; ++ks) {
      const int kb = ks*32 + lkof;
      const long af = *reinterpret_cast<const long*>(W4f + (size_t)lrow * HDIM + kb);
      const long b  = *reinterpret_cast<const long*>(&Hs[wave*16 + lrow][kb]);
      a4 = __builtin_amdgcn_mfma_f32_16x16x32_fp8_fp8(af, b, a4, 0, 0, 0);
    }
    // C[j][n]: lane holds rows j=(hq*4..+3) of vertex wave*16+lrow; j<3 at hq==0
    if (hq == 0) {
      dL[wave*16 + lrow][0] = a4[0] + b4p[0];
      dL[wave*16 + lrow][1] = a4[1] + b4p[1];
      dL[wave*16 + lrow][2] = a4[2] + b4p[2];
    }
  }
  __syncthreads();

  // ---- final: tanh, rotate back, write posed + delta ----
  if (tid < BM) {
    const int n = vbase + tid;
    if (n < N) {
      const float* rr = RbS + (size_t)n * 12;
      f32x4 q0 = __builtin_nontemporal_load(reinterpret_cast<const f32x4*>(rr));
      f32x4 q1 = __builtin_nontemporal_load(reinterpret_cast<const f32x4*>(rr + 4));
      f32x4 q2 = __builtin_nontemporal_load(reinterpret_cast<const f32x4*>(rr + 8));
      const float dl0 = 0.02f * tanhf(dL[tid][0]);
      const float dl1 = 0.02f * tanhf(dL[tid][1]);
      const float dl2 = 0.02f * tanhf(dL[tid][2]);
      const float dw0 = q0[0]*dl0 + q0[1]*dl1 + q0[2]*dl2;
      const float dw1 = q0[3]*dl0 + q1[0]*dl1 + q1[1]*dl2;
      const float dw2 = q1[2]*dl0 + q1[3]*dl1 + q2[0]*dl2;
      const float s0 = q2[1], s1 = q2[2], s2 = q2[3];
      const size_t o  = (size_t)n * 3;
      const size_t NB = (size_t)N * 3;
      out[o+0]      = s0 + dw0; out[o+1]      = s1 + dw1; out[o+2]      = s2 + dw2;
      out[2*NB+o+0] = dw0;      out[2*NB+o+1] = dw1;      out[2*NB+o+2] = dw2;
    }
  }
}

// ---------------- fallback: fused kernel (small workspace), bf16 ----------------
__global__ __launch_bounds__(512, 2) void deform_fused_kernel(
    const float* __restrict__ verts,
    const float* __restrict__ logits,
    const float* __restrict__ rotw,
    const unsigned short* __restrict__ W1t,
    const unsigned short* __restrict__ W2t,
    const unsigned short* __restrict__ W3t,
    const float* __restrict__ b1p, const float* __restrict__ b2p, const float* __restrict__ b3p,
    const float* __restrict__ W4, const float* __restrict__ b4p,
    float* __restrict__ out, int N) {

  __shared__ __align__(16) unsigned short Hbuf[BM][HST];
  __shared__ float rotL[KBONES*12];
  __shared__ float RbL[BM][9];
  __shared__ float skL[BM][3];

  const int tid = threadIdx.x;
  for (int i = tid; i < KBONES*12; i += 512) rotL[i] = rotw[i];
  __syncthreads();

  const int vbase = blockIdx.x * BM;

  if (tid < BM) {
    const int n = vbase + tid;
    if (n < N) {
      const float* lgp = logits + (size_t)n * KBONES;
      float ssum = 0.f;
      #pragma unroll 1
      for (int i = 0; i < 16; ++i) {
        const f32x4 z = reinterpret_cast<const f32x4*>(lgp)[i];
        ssum += __expf(z[0]) + __expf(z[1]) + __expf(z[2]) + __expf(z[3]);
      }
      float inv = 1.f / ssum;
      float M[9] = {0,0,0,0,0,0,0,0,0};
      float tb0 = 0.f, tb1 = 0.f, tb2 = 0.f;
      #pragma unroll 1
      for (int c = 0; c < 8; ++c) {
        const f32x4 za = reinterpret_cast<const f32x4*>(lgp)[2*c];
        const f32x4 zb = reinterpret_cast<const f32x4*>(lgp)[2*c+1];
        s16x8 sv;
        #pragma unroll
        for (int j = 0; j < 8; ++j) {
          const float zz = (j < 4) ? za[j] : zb[j-4];
          const float w = __expf(zz) * inv;
          sv[j] = (short)f2bf(w);
          const float* rk = &rotL[(c*8+j)*12];
          M[0] += w*rk[0]; M[1] += w*rk[1]; M[2] += w*rk[2];
          M[3] += w*rk[3]; M[4] += w*rk[4]; M[5] += w*rk[5];
          M[6] += w*rk[6]; M[7] += w*rk[7]; M[8] += w*rk[8];
          tb0 += w*rk[9]; tb1 += w*rk[10]; tb2 += w*rk[11];
        }
        *reinterpret_cast<s16x8*>(&Hbuf[tid][c*8]) = sv;
      }
      float vx = verts[(size_t)n*3+0], vy = verts[(size_t)n*3+1], vz = verts[(size_t)n*3+2];
      float p0 = M[0]*vx + M[1]*vy + M[2]*vz;
      float p1 = M[3]*vx + M[4]*vy + M[5]*vz;
      float p2 = M[6]*vx + M[7]*vy + M[8]*vz;
      float R[9];
      polar_rotation(M, R);
      const s16x8 z8 = {0,0,0,0,0,0,0,0};
      #pragma unroll
      for (int i = 8; i < 12; ++i) *reinterpret_cast<s16x8*>(&Hbuf[tid][i*8]) = z8;
      Hbuf[tid][64] = f2bf(R[0]*p0 + R[3]*p1 + R[6]*p2);
      Hbuf[tid][65] = f2bf(R[1]*p0 + R[4]*p1 + R[7]*p2);
      Hbuf[tid][66] = f2bf(R[2]*p0 + R[5]*p1 + R[8]*p2);
      #pragma unroll
      for (int e = 0; e < 9; ++e) RbL[tid][e] = R[e];
      skL[tid][0] = p0 + tb0; skL[tid][1] = p1 + tb1; skL[tid][2] = p2 + tb2;
    } else {
      const s16x8 z8 = {0,0,0,0,0,0,0,0};
      #pragma unroll
      for (int i = 0; i < 12; ++i) *reinterpret_cast<s16x8*>(&Hbuf[tid][i*8]) = z8;
    }
  }
  __syncthreads();

  const int wave = tid >> 6;
  const int lane = tid & 63;
  const int lrow = lane & 15;
  const int lkof = (lane >> 4) * 8;
  const int c0 = (wave*2+0)*16 + lrow;
  const int c1 = (wave*2+1)*16 + lrow;
  const f32x4 zf = {0.f,0.f,0.f,0.f};
  f32x4 acc[8][2];

  #pragma unroll
  for (int mt = 0; mt < 8; ++mt) { acc[mt][0] = zf; acc[mt][1] = zf; }
  #pragma unroll
  for (int ks = 0; ks < 3; ++ks) {
    const int kb = ks*32 + lkof;
    s16x8 bf0 = *reinterpret_cast<const s16x8*>(W1t + (size_t)c0 * KP1 + kb);
    s16x8 bf1 = *reinterpret_cast<const s16x8*>(W1t + (size_t)c1 * KP1 + kb);
    #pragma unroll
    for (int mt = 0; mt < 8; ++mt) {
      s16x8 af = *reinterpret_cast<const s16x8*>(&Hbuf[mt*16 + lrow][kb]);
      acc[mt][0] = __builtin_amdgcn_mfma_f32_16x16x32_bf16(af, bf0, acc[mt][0], 0, 0, 0);
      acc[mt][1] = __builtin_amdgcn_mfma_f32_16x16x32_bf16(af, bf1, acc[mt][1], 0, 0, 0);
    }
  }
  __syncthreads();
  {
    const float bb0 = b1p[c0], bb1 = b1p[c1];
    #pragma unroll
    for (int mt = 0; mt < 8; ++mt) {
      const int rbase = mt*16 + (lane>>4)*4;
      #pragma unroll
      for (int r = 0; r < 4; ++r) {
        Hbuf[rbase+r][c0] = f2bf(fmaxf(acc[mt][0][r] + bb0, 0.f));
        Hbuf[rbase+r][c1] = f2bf(fmaxf(acc[mt][1][r] + bb1, 0.f));
      }
    }
  }
  __syncthreads();

  for (int layer = 0; layer < 2; ++layer) {
    const unsigned short* Wt = (layer == 0) ? W2t : W3t;
    const float* bp = (layer == 0) ? b2p : b3p;
    #pragma unroll
    for (int mt = 0; mt < 8; ++mt) { acc[mt][0] = zf; acc[mt][1] = zf; }
    #pragma unroll
    for (int ks = 0; ks < 8; ++ks) {
      const int kb = ks*32 + lkof;
      s16x8 bf0 = *reinterpret_cast<const s16x8*>(Wt + (size_t)c0 * HDIM + kb);
      s16x8 bf1 = *reinterpret_cast<const s16x8*>(Wt + (size_t)c1 * HDIM + kb);
      #pragma unroll
      for (int mt = 0; mt < 8; ++mt) {
        s16x8 af = *reinterpret_cast<const s16x8*>(&Hbuf[mt*16 + lrow][kb]);
        acc[mt][0] = __builtin_amdgcn_mfma_f32_16x16x32_bf16(af, bf0, acc[mt][0], 0, 0, 0);
        acc[mt][1] = __builtin_amdgcn_mfma_f32_16x16x32_bf16(af, bf1, acc[mt][1], 0, 0, 0);
      }
    }
    __syncthreads();
    const float bb0 = bp[c0], bb1 = bp[c1];
    #pragma unroll
    for (int mt = 0; mt < 8; ++mt) {
      const int rbase = mt*16 + (lane>>4)*4;
      #pragma unroll
      for (int r = 0; r < 4; ++r) {
        Hbuf[rbase+r][c0] = f2bf(fmaxf(acc[mt][0][r] + bb0, 0.f));
        Hbuf[rbase+r][c1] = f2bf(fmaxf(acc[mt][1][r] + bb1, 0.f));
      }
    }
    __syncthreads();
  }

  if (tid < BM) {
    const int n = vbase + tid;
    if (n < N) {
      float d0 = b4p[0], d1 = b4p[1], d2 = b4p[2];
      const s16x8* hp = reinterpret_cast<const s16x8*>(&Hbuf[tid][0]);
      #pragma unroll
      for (int i = 0; i < 32; ++i) {
        s16x8 h8 = hp[i];
        #pragma unroll
        for (int j = 0; j < 8; ++j) {
          const float h = bf2f((unsigned short)h8[j]);
          const int c = i*8 + j;
          d0 += h * W4[c*3+0];
          d1 += h * W4[c*3+1];
          d2 += h * W4[c*3+2];
        }
      }
      const float dl0 = 0.02f * tanhf(d0);
      const float dl1 = 0.02f * tanhf(d1);
      const float dl2 = 0.02f * tanhf(d2);
      float R[9];
      #pragma unroll
      for (int e = 0; e < 9; ++e) R[e] = RbL[tid][e];
      const float dw0 = R[0]*dl0 + R[1]*dl1 + R[2]*dl2;
      const float dw1 = R[3]*dl0 + R[4]*dl1 + R[5]*dl2;
      const float dw2 = R[6]*dl0 + R[7]*dl1 + R[8]*dl2;
      const float s0 = skL[tid][0], s1 = skL[tid][1], s2 = skL[tid][2];
      const size_t o  = (size_t)n * 3;
      const size_t NB = (size_t)N * 3;
      out[o+0]      = s0 + dw0; out[o+1]      = s1 + dw1; out[o+2]      = s2 + dw2;
      out[NB+o+0]   = s0;       out[NB+o+1]   = s1;       out[NB+o+2]   = s2;
      out[2*NB+o+0] = dw0;      out[2*NB+o+1] = dw1;      out[2*NB+o+2] = dw2;
    }
  }
}

extern "C" void kernel_launch(void* const* d_in, const int* in_sizes, int n_in,
                              void* d_out, int out_size, void* d_ws, size_t ws_size,
                              hipStream_t stream) {
  const float* verts  = (const float*)d_in[0];
  const float* logits = (const float*)d_in[1];
  const float* rot6d  = (const float*)d_in[2];
  const float* trans  = (const float*)d_in[3];
  const float* W1 = (const float*)d_in[4];
  const float* b1 = (const float*)d_in[5];
  const float* W2 = (const float*)d_in[6];
  const float* b2 = (const float*)d_in[7];
  const float* W3 = (const float*)d_in[8];
  const float* b3 = (const float*)d_in[9];
  const float* W4 = (const float*)d_in[10];
  const float* b4 = (const float*)d_in[11];
  float* out = (float*)d_out;
  const int N = in_sizes[0] / 3;
  const size_t N128 = (((size_t)N + 127) / 128) * 128;

  char* ws = (char*)d_ws;
  const size_t o_rotw = 0;                             // 3072
  const size_t o_w1t  = 4096;                          // 49152 (bf16, fallback)
  const size_t o_w2t  = o_w1t + 49152;                 // 131072
  const size_t o_w3t  = o_w2t + 131072;                // 131072
  const size_t o_w1f  = o_w3t + 131072;                // 24576 (fp8)
  const size_t o_w2f  = o_w1f + 24576;                 // 65536
  const size_t o_w3f  = o_w2f + 65536;                 // 65536
  const size_t o_w4f  = o_w3f + 65536;                 // 4096
  const size_t o_rbs  = (o_w4f + 4096 + 255) & ~(size_t)255;   // N*48
  const size_t o_x    = (o_rbs + (size_t)N*48 + 255) & ~(size_t)255;
  const size_t need   = o_x + N128 * KP1;              // fp8 X: 96 B/row

  float*          rotw = (float*)(ws + o_rotw);
  unsigned short* W1t  = (unsigned short*)(ws + o_w1t);
  unsigned short* W2t  = (unsigned short*)(ws + o_w2t);
  unsigned short* W3t  = (unsigned short*)(ws + o_w3t);
  unsigned char*  W1f  = (unsigned char*)(ws + o_w1f);
  unsigned char*  W2f  = (unsigned char*)(ws + o_w2f);
  unsigned char*  W3f  = (unsigned char*)(ws + o_w3f);
  unsigned char*  W4f  = (unsigned char*)(ws + o_w4f);
  float*          RbS  = (float*)(ws + o_rbs);
  unsigned char*  Xg   = (unsigned char*)(ws + o_x);

  prep_kernel<<<128, 256, 0, stream>>>(rot6d, trans, W1, W2, W3, W4,
                                       rotw, W1t, W2t, W3t, W1f, W2f, W3f, W4f);

  if (ws_size >= need) {
    const int grid2 = (N + 255) / 256;
    vertex_kernel<<<grid2, 256, 0, stream>>>(verts, logits, rotw, Xg, RbS, out, N);
    const int grid3 = (int)(N128 / 128);
    mlp_kernel<<<grid3, 512, 0, stream>>>(Xg, W1f, W2f, W3f, W4f,
                                          b1, b2, b3, b4, RbS, out, N);
  } else {
    const int grid = (N + BM - 1) / BM;
    deform_fused_kernel<<<grid, 512, 0, stream>>>(verts, logits, rotw, W1t, W2t, W3t,
                                                  b1, b2, b3, W4, b4, out, N);
  }
}